// Round 12
// baseline (570.713 us; speedup 1.0000x reference)
//
#include <hip/hip_runtime.h>
#include <hip/hip_bf16.h>
#include <cstdint>

#define F_IN 256
#define C 128
#define NBUK_MAX 320     // supports NODES <= 81920 (bucket = dst >> 8)
#define CHUNK 4096       // edges per partition block
#define CAP 12288        // per-bucket slab capacity (mean ~8180, max ~8500)

typedef short bf8_t __attribute__((ext_vector_type(8)));   // 8 bf16 bit-patterns (4 VGPRs)
typedef float f4_t  __attribute__((ext_vector_type(4)));

static inline size_t align256(size_t x) { return (x + 255) & ~(size_t)255; }

static __device__ inline unsigned pack_bf16(float a, float b) {
    __hip_bfloat162 h = __float22bfloat162_rn(make_float2(a, b));
    return *(unsigned*)&h;
}

static __device__ inline bf8_t pack8(float4 u0, float4 u1) {
    union { unsigned u[4]; bf8_t v; } r;
    r.u[0] = pack_bf16(u0.x, u0.y);
    r.u[1] = pack_bf16(u0.z, u0.w);
    r.u[2] = pack_bf16(u1.x, u1.y);
    r.u[3] = pack_bf16(u1.z, u1.w);
    return r.v;
}

// ---------------- union: edge partition  ∪  GEMM1 (G' = bf16(X @ W1), unscaled) -------
// R10/R11-proven. GEMM1 depends only on x/Wsw1, so its blocks ride the latency-bound
// partition blocks in one dispatch; dinv scaling deferred to agg1 (SRCSCALE).
__global__ __launch_bounds__(256) void part_gemm1_kernel(
        const int* __restrict__ src, const int* __restrict__ dst,
        int* __restrict__ cntb, int* __restrict__ ebuf, int E, int nblk_part,
        const float* __restrict__ X, const __hip_bfloat16* __restrict__ Wsw,
        __hip_bfloat16* __restrict__ G, int M) {
    __shared__ __align__(16) char smem[36864];
    const int tid = threadIdx.x;

    if ((int)blockIdx.x < nblk_part) {
        // ---------------- partition path ----------------
        int* hist = (int*)smem;                       // 320 ints
        int* base = hist + NBUK_MAX;                  // 320
        int* gbase = base + NBUK_MAX;                 // 320
        int2* stage = (int2*)(smem + 4096);           // 4096 int2 = 32 KB
        const int e0 = blockIdx.x * CHUNK;
        const int cnt = min(CHUNK, E - e0);

        for (int i = tid; i < NBUK_MAX; i += 256) hist[i] = 0;
        __syncthreads();

        int2 ev[CHUNK / 256];
        int mo[CHUNK / 256];
#pragma unroll
        for (int k = 0; k < CHUNK / 256; ++k) {
            int e = e0 + k * 256 + tid;
            if (e < E) {
                int2 v;
                v.x = src[e];
                v.y = dst[e];
                ev[k] = v;
                mo[k] = atomicAdd(&hist[v.y >> 8], 1);
            }
        }
        __syncthreads();
        if (tid < 64) {
            int acc[5];
            int s = 0;
#pragma unroll
            for (int j = 0; j < 5; ++j) {
                acc[j] = s;
                s += hist[tid * 5 + j];
            }
            int tot = s;
#pragma unroll
            for (int d = 1; d < 64; d <<= 1) {
                int o = __shfl_up(tot, d);
                if (tid >= d) tot += o;
            }
            int excl = tot - s;
#pragma unroll
            for (int j = 0; j < 5; ++j) base[tid * 5 + j] = excl + acc[j];
        }
        __syncthreads();
        for (int i = tid; i < NBUK_MAX; i += 256) {
            int h = hist[i];
            gbase[i] = h ? atomicAdd(&cntb[i], h) : 0;
        }
        __syncthreads();
#pragma unroll
        for (int k = 0; k < CHUNK / 256; ++k) {
            int e = e0 + k * 256 + tid;
            if (e < E) stage[base[ev[k].y >> 8] + mo[k]] = ev[k];
        }
        __syncthreads();
        for (int i = tid; i < cnt; i += 256) {
            int2 e = stage[i];
            int b = e.y >> 8;
            ebuf[(size_t)b * CAP + gbase[b] + (i - base[b])] = ((e.y & 255) << 24) | e.x;
        }
    } else {
        // ---------------- GEMM1 path (K = 256, fp32 in, unscaled out) ----------------
        char* lds = smem;   // 32 KB used
        const int gb = blockIdx.x - nblk_part;
        const int l = tid & 63;
        const int w = tid >> 6;
        const int lm = l & 15;
        const int lk = (l >> 4) * 8;
        const int row0 = gb * 128 + w * 32;
        const int K = F_IN;

        f4_t acc[2][8] = {};
        const float* xf[2];
#pragma unroll
        for (int mt = 0; mt < 2; ++mt) {
            int r = min(row0 + mt * 16 + lm, M - 1);
            xf[mt] = X + (size_t)r * K + lk;
        }
        float4 cf[2][2];
#pragma unroll
        for (int mt = 0; mt < 2; ++mt) {
            cf[mt][0] = *(const float4*)(xf[mt]);
            cf[mt][1] = *(const float4*)(xf[mt] + 4);
        }
        for (int s = 0; s < 8; ++s) {
            if ((s & 3) == 0) {
                if (s) __syncthreads();
                const char* wsrc = (const char*)Wsw + (size_t)s * 8192;
                for (int o = tid * 16; o < 32768; o += 256 * 16)
                    *(uint4*)(lds + o) = *(const uint4*)(wsrc + o);
                __syncthreads();
            }
            float4 nf[2][2];
            if (s + 1 < 8) {
#pragma unroll
                for (int mt = 0; mt < 2; ++mt) {
                    nf[mt][0] = *(const float4*)(xf[mt] + (s + 1) * 32);
                    nf[mt][1] = *(const float4*)(xf[mt] + (s + 1) * 32 + 4);
                }
            }
            bf8_t a[2];
#pragma unroll
            for (int mt = 0; mt < 2; ++mt)
                a[mt] = pack8(cf[mt][0], cf[mt][1]);
            const char* bbase = lds + ((size_t)((s & 3) * 8) * 64 + l) * 16;
#pragma unroll
            for (int u = 0; u < 8; ++u) {
                bf8_t b = *(const bf8_t*)(bbase + (size_t)u * 64 * 16);
#pragma unroll
                for (int mt = 0; mt < 2; ++mt)
                    acc[mt][u] = __builtin_amdgcn_mfma_f32_16x16x32_bf16(a[mt], b, acc[mt][u], 0, 0, 0);
            }
            if (s + 1 < 8) {
#pragma unroll
                for (int mt = 0; mt < 2; ++mt) {
                    cf[mt][0] = nf[mt][0];
                    cf[mt][1] = nf[mt][1];
                }
            }
        }
#pragma unroll
        for (int mt = 0; mt < 2; ++mt) {
            int rbase = row0 + mt * 16 + (l >> 4) * 4;
#pragma unroll
            for (int r = 0; r < 4; ++r) {
                int row = rbase + r;
                if (row < M) {
#pragma unroll
                    for (int u = 0; u < 8; ++u)
                        G[(size_t)row * C + u * 16 + lm] = __float2bfloat16(acc[mt][u][r]);
                }
            }
        }
    }
}

// ---------------- CSR build with inline bucket scan (R11-proven) ----------------
__global__ __launch_bounds__(256) void csr_build_kernel(const int* __restrict__ ebuf,
                                                        const int* __restrict__ cntb,
                                                        int nbuk,
                                                        int* __restrict__ offs,
                                                        float* __restrict__ dinv,
                                                        int* __restrict__ csr, int nodes) {
    __shared__ int hist[NBUK_MAX];
    __shared__ int basep[NBUK_MAX];
    __shared__ int deg[256];
    __shared__ int p[256];
    __shared__ int pre[257];
    __shared__ int cur[256];
    const int b = blockIdx.x;
    const int n0 = b << 8;
    const int ncnt = min(256, nodes - n0);
    const int tid = threadIdx.x;

    for (int bk = tid; bk < NBUK_MAX; bk += 256)
        hist[bk] = (bk < nbuk) ? cntb[bk] : 0;
    __syncthreads();
    if (tid < 64) {
        int acc[5];
        int s = 0;
#pragma unroll
        for (int j = 0; j < 5; ++j) {
            acc[j] = s;
            s += hist[tid * 5 + j];
        }
        int tot = s;
#pragma unroll
        for (int d = 1; d < 64; d <<= 1) {
            int o = __shfl_up(tot, d);
            if (tid >= d) tot += o;
        }
        int excl = tot - s;
#pragma unroll
        for (int j = 0; j < 5; ++j) basep[tid * 5 + j] = excl + acc[j];
    }
    __syncthreads();
    const int eb = basep[b];
    const int cntE = hist[b];
    const int* slab = ebuf + (size_t)b * CAP;

    deg[tid] = 0;
    __syncthreads();
    for (int k = tid; k < cntE; k += 256)
        atomicAdd(&deg[(unsigned)slab[k] >> 24], 1);
    __syncthreads();
    p[tid] = deg[tid];
    __syncthreads();
    for (int d = 1; d < 256; d <<= 1) {
        int v = (tid >= d) ? p[tid - d] : 0;
        __syncthreads();
        p[tid] += v;
        __syncthreads();
    }
    pre[tid + 1] = p[tid];
    if (tid == 0) pre[0] = 0;
    __syncthreads();

    for (int i = tid; i <= ncnt; i += 256)
        offs[n0 + i] = eb + pre[i] + n0 + i;
    if (tid < ncnt) {
        dinv[n0 + tid] = rsqrtf((float)(deg[tid] + 1));
        csr[eb + pre[tid] + n0 + tid] = n0 + tid;   // self-loop head
    }
    cur[tid] = 0;
    __syncthreads();
    for (int k = tid; k < cntE; k += 256) {
        int v = slab[k];
        int loc = (unsigned)v >> 24;
        int q = atomicAdd(&cur[loc], 1);
        csr[eb + pre[loc] + n0 + loc + 1 + q] = v & 0xFFFFFF;
    }
}

// ---------------- W swizzle ----------------
static __device__ inline void swz_one(const float* __restrict__ W,
                                      __hip_bfloat16* __restrict__ Wsw, int i) {
    int l = i & 63;
    int u = (i >> 6) & 7;
    int t = i >> 9;
    int krow = t * 32 + (l >> 4) * 8;
    int col = u * 16 + (l & 15);
    unsigned packed[4];
#pragma unroll
    for (int j = 0; j < 4; ++j) {
        float a = W[(size_t)(krow + 2 * j) * C + col];
        float b = W[(size_t)(krow + 2 * j + 1) * C + col];
        packed[j] = pack_bf16(a, b);
    }
    uint4 o = make_uint4(packed[0], packed[1], packed[2], packed[3]);
    *(uint4*)(Wsw + (size_t)i * 8) = o;
}

__global__ __launch_bounds__(256) void wswz_all_kernel(const float* __restrict__ W1,
                                                       const float* __restrict__ W2,
                                                       const float* __restrict__ W3,
                                                       __hip_bfloat16* __restrict__ Wsw1,
                                                       __hip_bfloat16* __restrict__ Wsw2,
                                                       __hip_bfloat16* __restrict__ Wsw3) {
    int i = blockIdx.x * blockDim.x + threadIdx.x;
    if (i < 4096)      swz_one(W1, Wsw1, i);
    else if (i < 6144) swz_one(W2, Wsw2, i - 4096);
    else if (i < 8192) swz_one(W3, Wsw3, i - 6144);
}

// ---------------- shared GEMM (K=128) block body, 16KB chunked W staging ----------------
// 2 chunks x 16KB so union dispatches keep agg occupancy (LDS 16KB -> 8 blocks/CU).
static __device__ inline void gemm128_body(const __hip_bfloat16* __restrict__ Xv,
                                           const __hip_bfloat16* __restrict__ Wsw,
                                           const float* __restrict__ dinv,
                                           __hip_bfloat16* __restrict__ G2,
                                           int M, int row0blk, int tid, char* lds) {
    const int l = tid & 63;
    const int w = tid >> 6;
    const int lm = l & 15;
    const int lk = (l >> 4) * 8;
    const int row0 = row0blk + w * 32;

    f4_t acc[2][8] = {};
    const __hip_bfloat16* xb[2];
#pragma unroll
    for (int mt = 0; mt < 2; ++mt) {
        int r = min(row0 + mt * 16 + lm, M - 1);
        xb[mt] = Xv + (size_t)r * C + lk;
    }
    bf8_t cb[2];
#pragma unroll
    for (int mt = 0; mt < 2; ++mt)
        cb[mt] = *(const bf8_t*)(xb[mt]);

    for (int c = 0; c < 2; ++c) {
        if (c) __syncthreads();
        for (int o = tid * 16; o < 16384; o += 256 * 16)
            *(uint4*)(lds + o) = *(const uint4*)((const char*)Wsw + (size_t)c * 16384 + o);
        __syncthreads();
        for (int s2 = 0; s2 < 2; ++s2) {
            const int s = c * 2 + s2;
            bf8_t nb[2];
            if (s + 1 < 4) {
#pragma unroll
                for (int mt = 0; mt < 2; ++mt)
                    nb[mt] = *(const bf8_t*)(xb[mt] + (s + 1) * 32);
            }
            const char* bbase = lds + ((size_t)(s2 * 8) * 64 + l) * 16;
#pragma unroll
            for (int u = 0; u < 8; ++u) {
                bf8_t b = *(const bf8_t*)(bbase + (size_t)u * 64 * 16);
#pragma unroll
                for (int mt = 0; mt < 2; ++mt)
                    acc[mt][u] = __builtin_amdgcn_mfma_f32_16x16x32_bf16(cb[mt], b, acc[mt][u], 0, 0, 0);
            }
            if (s + 1 < 4) {
#pragma unroll
                for (int mt = 0; mt < 2; ++mt)
                    cb[mt] = nb[mt];
            }
        }
    }

#pragma unroll
    for (int mt = 0; mt < 2; ++mt) {
        int rbase = row0 + mt * 16 + (l >> 4) * 4;
#pragma unroll
        for (int r = 0; r < 4; ++r) {
            int row = rbase + r;
            if (row < M) {
                float dv = dinv[row];
#pragma unroll
                for (int u = 0; u < 8; ++u) {
                    float v = acc[mt][u][r] * dv;
                    G2[(size_t)row * C + u * 16 + lm] = __float2bfloat16(v);
                }
            }
        }
    }
}

__global__ __launch_bounds__(256) void mfma_gemm_kernel(const __hip_bfloat16* __restrict__ Xv,
                                                        const __hip_bfloat16* __restrict__ Wsw,
                                                        const float* __restrict__ dinv,
                                                        __hip_bfloat16* __restrict__ G2,
                                                        int rowBase, int M) {
    __shared__ __align__(16) char lds[16384];
    gemm128_body(Xv, Wsw, dinv, G2, M, rowBase + blockIdx.x * 128, threadIdx.x, lds);
}

// ---------------- shared gather helpers (R10/R11-proven) ----------------
static __device__ inline void unpack_add(uint4 v, float* acc) {
    const __hip_bfloat162* hh = (const __hip_bfloat162*)&v;
#pragma unroll
    for (int t = 0; t < 4; ++t) {
        float2 f = __bfloat1622float2(hh[t]);
        acc[2 * t]     += f.x;
        acc[2 * t + 1] += f.y;
    }
}

static __device__ inline void unpack_fma(uint4 v, float dv, float* acc) {
    const __hip_bfloat162* hh = (const __hip_bfloat162*)&v;
#pragma unroll
    for (int t = 0; t < 4; ++t) {
        float2 f = __bfloat1622float2(hh[t]);
        acc[2 * t]     = fmaf(f.x, dv, acc[2 * t]);
        acc[2 * t + 1] = fmaf(f.y, dv, acc[2 * t + 1]);
    }
}

template <bool SS>
static __device__ inline void gather_rows(const char* __restrict__ Gb,
                                          const int* __restrict__ csr,
                                          const float* __restrict__ dinv,
                                          int beg, int end, int l, int g,
                                          unsigned qoff, float* acc) {
    for (int base = beg; base < end; base += 64) {
        const int cnt = min(64, end - base);
        int myidx = (l < cnt) ? csr[base + l] : 0;
        float mydv = SS ? dinv[myidx] : 1.f;
        int j = 0;
        for (; j + 16 <= cnt; j += 16) {
            int i0 = __shfl(myidx, j + g);
            int i1 = __shfl(myidx, j + 4 + g);
            int i2 = __shfl(myidx, j + 8 + g);
            int i3 = __shfl(myidx, j + 12 + g);
            uint4 v0 = *(const uint4*)(Gb + (((unsigned)i0 << 8) | qoff));
            uint4 v1 = *(const uint4*)(Gb + (((unsigned)i1 << 8) | qoff));
            uint4 v2 = *(const uint4*)(Gb + (((unsigned)i2 << 8) | qoff));
            uint4 v3 = *(const uint4*)(Gb + (((unsigned)i3 << 8) | qoff));
            if (SS) {
                float d0 = __shfl(mydv, j + g);
                float d1 = __shfl(mydv, j + 4 + g);
                float d2 = __shfl(mydv, j + 8 + g);
                float d3 = __shfl(mydv, j + 12 + g);
                unpack_fma(v0, d0, acc); unpack_fma(v1, d1, acc);
                unpack_fma(v2, d2, acc); unpack_fma(v3, d3, acc);
            } else {
                unpack_add(v0, acc); unpack_add(v1, acc);
                unpack_add(v2, acc); unpack_add(v3, acc);
            }
        }
        if (j + 8 <= cnt) {
            int i0 = __shfl(myidx, j + g);
            int i1 = __shfl(myidx, j + 4 + g);
            uint4 v0 = *(const uint4*)(Gb + (((unsigned)i0 << 8) | qoff));
            uint4 v1 = *(const uint4*)(Gb + (((unsigned)i1 << 8) | qoff));
            if (SS) {
                float d0 = __shfl(mydv, j + g);
                float d1 = __shfl(mydv, j + 4 + g);
                unpack_fma(v0, d0, acc); unpack_fma(v1, d1, acc);
            } else {
                unpack_add(v0, acc); unpack_add(v1, acc);
            }
            j += 8;
        }
        for (; j < cnt; j += 4) {
            int i0 = __shfl(myidx, j + g);
            float sc = (j + g < cnt) ? 1.f : 0.f;
            if (SS) sc *= __shfl(mydv, j + g);
            uint4 v0 = *(const uint4*)(Gb + (((unsigned)i0 << 8) | qoff));
            unpack_fma(v0, sc, acc);
        }
    }
}

// ---------------- agg node body (shared by standalone + union kernels) ----------------
template <bool SS>
static __device__ inline void agg_node_body(const __hip_bfloat16* __restrict__ G,
                                            const int* __restrict__ csr,
                                            const int* __restrict__ offs,
                                            const float* __restrict__ dinv,
                                            const float* __restrict__ bias,
                                            __hip_bfloat16* __restrict__ A,
                                            int node, int tid) {
    const int l = tid & 63;
    const int g = l >> 4;
    const unsigned qoff = (l & 15) * 16;
    const int beg = offs[node], end = offs[node + 1];
    float acc[8] = {};
    gather_rows<SS>((const char*)G, csr, dinv, beg, end, l, g, qoff, acc);

#pragma unroll
    for (int t = 0; t < 8; ++t) {
        acc[t] += __shfl_xor(acc[t], 16);
        acc[t] += __shfl_xor(acc[t], 32);
    }

    const float d = dinv[node];
    if (g == 0) {
        float bb[8];
        *(float4*)bb       = *(const float4*)(bias + qoff / 2);
        *(float4*)(bb + 4) = *(const float4*)(bias + qoff / 2 + 4);
        unsigned pk[4];
#pragma unroll
        for (int t = 0; t < 4; ++t) {
            float x0 = fmaxf(fmaf(acc[2 * t],     d, bb[2 * t]),     0.f);
            float x1 = fmaxf(fmaf(acc[2 * t + 1], d, bb[2 * t + 1]), 0.f);
            pk[t] = pack_bf16(x0, x1);
        }
        *(uint4*)((char*)A + (size_t)node * 256 + qoff) = make_uint4(pk[0], pk[1], pk[2], pk[3]);
    }
}

// standalone agg over nodes [nodeBase, ...): 4 nodes / 256-thread block
template <bool SS>
__global__ __launch_bounds__(256) void agg_kernel(const __hip_bfloat16* __restrict__ G,
                                                  const int* __restrict__ csr,
                                                  const int* __restrict__ offs,
                                                  const float* __restrict__ dinv,
                                                  const float* __restrict__ bias,
                                                  __hip_bfloat16* __restrict__ A,
                                                  int nodeBase, int nodes) {
    const int node = nodeBase + blockIdx.x * 4 + (threadIdx.x >> 6);
    if (node >= nodes) return;
    agg_node_body<SS>(G, csr, offs, dinv, bias, A, node, threadIdx.x);
}

// ---------------- union: agg second-half ∪ next-layer GEMM first-half ----------------
// agg blocks gather Gsrc (all rows, complete) and write A rows [nodeBase,..).
// gemm blocks read A rows [0, nAggDone) (written by the previous 'a' dispatch) and
// write Gdst (ping-pong buffer != Gsrc) rows [0, nGemmBlk*128). Disjoint traffic.
template <bool SS>
__global__ __launch_bounds__(256) void agg_gemm_union_kernel(
        const __hip_bfloat16* __restrict__ Gsrc,
        const int* __restrict__ csr, const int* __restrict__ offs,
        const float* __restrict__ dinv, const float* __restrict__ bias,
        __hip_bfloat16* __restrict__ A, int nodeBase, int nodes, int nAggBlk,
        const __hip_bfloat16* __restrict__ Xv, const __hip_bfloat16* __restrict__ Wsw,
        __hip_bfloat16* __restrict__ Gdst) {
    __shared__ __align__(16) char lds[16384];
    const int tid = threadIdx.x;
    if ((int)blockIdx.x < nAggBlk) {
        const int node = nodeBase + blockIdx.x * 4 + (tid >> 6);
        if (node >= nodes) return;
        agg_node_body<SS>(Gsrc, csr, offs, dinv, bias, A, node, tid);
    } else {
        const int gb = blockIdx.x - nAggBlk;
        gemm128_body(Xv, Wsw, dinv, Gdst, nodes, gb * 128, tid, lds);
    }
}

// ---------------- union: agg3 second-half ∪ pool over A1+A2 ----------------
__global__ __launch_bounds__(256) void agg_pool12_union_kernel(
        const __hip_bfloat16* __restrict__ Gsrc,
        const int* __restrict__ csr, const int* __restrict__ offs,
        const float* __restrict__ dinv, const float* __restrict__ bias,
        __hip_bfloat16* __restrict__ A3, int nodeBase, int nodes, int nAggBlk,
        const __hip_bfloat16* __restrict__ S1, const __hip_bfloat16* __restrict__ S2,
        const int* __restrict__ mask, float* __restrict__ pooled, int N, int nbx) {
    const int tid = threadIdx.x;
    if ((int)blockIdx.x < nAggBlk) {
        const int node = nodeBase + blockIdx.x * 4 + (tid >> 6);
        if (node >= nodes) return;
        agg_node_body<false>(Gsrc, csr, offs, dinv, bias, A3, node, tid);
    } else {
        const int pb = blockIdx.x - nAggBlk;
        const int bx = pb % nbx;
        const int by = pb / nbx;
        const int l = tid & 63;
        const int w = tid >> 6;
        const int c0 = l * 2;
        const int n0 = bx * 128;
        const int lim = min(n0 + 128, N);
        float ax = 0.f, ay = 0.f;
        for (int n = n0 + w; n < lim; n += 4) {
            if (mask[by * N + n]) {
                size_t o = ((size_t)by * N + n) * C + c0;
                float2 f1 = __bfloat1622float2(*(const __hip_bfloat162*)(S1 + o));
                float2 f2 = __bfloat1622float2(*(const __hip_bfloat162*)(S2 + o));
                ax += f1.x + f2.x;
                ay += f1.y + f2.y;
            }
        }
        atomicAdd(&pooled[by * C + c0], ax);
        atomicAdd(&pooled[by * C + c0 + 1], ay);
    }
}

// ---------------- pool over A3 only ----------------
__global__ __launch_bounds__(64) void pool1_kernel(const __hip_bfloat16* __restrict__ S,
                                                   const int* __restrict__ mask,
                                                   float* __restrict__ pooled, int N) {
    const int b = blockIdx.y;
    const int n0 = blockIdx.x * 128;
    const int c0 = threadIdx.x * 2;
    const int lim = min(n0 + 128, N);
    float ax = 0.f, ay = 0.f;
    for (int n = n0; n < lim; ++n) {
        if (mask[b * N + n]) {
            size_t o = ((size_t)b * N + n) * C + c0;
            float2 f = __bfloat1622float2(*(const __hip_bfloat162*)(S + o));
            ax += f.x;
            ay += f.y;
        }
    }
    atomicAdd(&pooled[b * C + c0], ax);
    atomicAdd(&pooled[b * C + c0 + 1], ay);
}

// ---------------- MLP head: [4,128]->256->64->16->1 ----------------
__global__ __launch_bounds__(256) void mlp_kernel(const float* __restrict__ pooled,
        const float* __restrict__ lw1, const float* __restrict__ lb1,
        const float* __restrict__ lw2, const float* __restrict__ lb2,
        const float* __restrict__ lw3, const float* __restrict__ lb3,
        const float* __restrict__ lw4, const float* __restrict__ lb4,
        float* __restrict__ out) {
    __shared__ float p[4 * 128];
    __shared__ float z1[4 * 256];
    __shared__ float z2[4 * 64];
    __shared__ float z3[4 * 16];
    const int tid = threadIdx.x;
    for (int i = tid; i < 4 * 128; i += 256) p[i] = pooled[i];
    __syncthreads();
    for (int o = tid; o < 4 * 256; o += 256) {
        int b = o >> 8, j = o & 255;
        float s = lb1[j];
        for (int k = 0; k < 128; ++k) s += p[b * 128 + k] * lw1[k * 256 + j];
        z1[o] = fmaxf(s, 0.f);
    }
    __syncthreads();
    for (int o = tid; o < 4 * 64; o += 256) {
        int b = o >> 6, j = o & 63;
        float s = lb2[j];
        for (int k = 0; k < 256; ++k) s += z1[b * 256 + k] * lw2[k * 64 + j];
        z2[o] = fmaxf(s, 0.f);
    }
    __syncthreads();
    if (tid < 64) {
        int b = tid >> 4, j = tid & 15;
        float s = lb3[j];
        for (int k = 0; k < 64; ++k) s += z2[b * 64 + k] * lw3[k * 16 + j];
        z3[tid] = fmaxf(s, 0.f);
    }
    __syncthreads();
    if (tid < 4) {
        float s = lb4[0];
        for (int k = 0; k < 16; ++k) s += z3[tid * 16 + k] * lw4[k];
        out[tid] = s;
    }
}

// ---------------- launcher ----------------

extern "C" void kernel_launch(void* const* d_in, const int* in_sizes, int n_in,
                              void* d_out, int out_size, void* d_ws, size_t ws_size,
                              hipStream_t stream) {
    const float* x    = (const float*)d_in[0];
    const int*   ei   = (const int*)d_in[1];
    const int*   pmask = (const int*)d_in[2];
    const float* W1 = (const float*)d_in[3];  const float* b1 = (const float*)d_in[4];
    const float* W2 = (const float*)d_in[5];  const float* b2 = (const float*)d_in[6];
    const float* W3 = (const float*)d_in[7];  const float* b3 = (const float*)d_in[8];
    const float* lw1 = (const float*)d_in[9];  const float* lb1 = (const float*)d_in[10];
    const float* lw2 = (const float*)d_in[11]; const float* lb2 = (const float*)d_in[12];
    const float* lw3 = (const float*)d_in[13]; const float* lb3 = (const float*)d_in[14];
    const float* lw4 = (const float*)d_in[15]; const float* lb4 = (const float*)d_in[16];
    float* out = (float*)d_out;

    const int E = in_sizes[1] / 2;
    const int NODES = in_sizes[0] / F_IN;
    const int NB = 4;
    const int NPER = NODES / NB;   // 17000
    const int NBUK = (NODES + 255) >> 8;
    const int NBLK = (E + CHUNK - 1) / CHUNK;
    const int* esrc = ei;
    const int* edst = ei + E;

    char* w = (char*)d_ws;
    size_t off = 0;
    auto alloc = [&](size_t bytes) -> void* {
        void* p = w + off;
        off = align256(off + bytes);
        return p;
    };
    float* dinv = (float*)alloc((size_t)NODES * 4);
    int*   offs = (int*)  alloc((size_t)(NODES + 1) * 4);
    int*   cntb = (int*)  alloc((size_t)NBUK * 4);
    int*   ebuf = (int*)  alloc((size_t)NBUK * CAP * 4);   // packed 4B slab entries
    int*   csr  = (int*)  alloc((size_t)(E + NODES) * 4);
    __hip_bfloat16* GA  = (__hip_bfloat16*)alloc((size_t)NODES * C * 2);
    __hip_bfloat16* GB  = (__hip_bfloat16*)alloc((size_t)NODES * C * 2);
    __hip_bfloat16* A1  = (__hip_bfloat16*)alloc((size_t)NODES * C * 2);
    __hip_bfloat16* A2  = (__hip_bfloat16*)alloc((size_t)NODES * C * 2);
    __hip_bfloat16* A3  = (__hip_bfloat16*)alloc((size_t)NODES * C * 2);
    __hip_bfloat16* Wsw1 = (__hip_bfloat16*)alloc((size_t)F_IN * C * 2);
    __hip_bfloat16* Wsw2 = (__hip_bfloat16*)alloc((size_t)C * C * 2);
    __hip_bfloat16* Wsw3 = (__hip_bfloat16*)alloc((size_t)C * C * 2);
    float* pooled = (float*)alloc((size_t)4 * C * 4);
    (void)ws_size; (void)n_in; (void)out_size;

    hipMemsetAsync(cntb,   0, (size_t)NBUK * 4, stream);
    hipMemsetAsync(pooled, 0, (size_t)4 * C * 4, stream);

    const int gbl = (NODES + 127) / 128;     // 532
    const int gA  = gbl / 2;                 // 266 -> rows [0, H)
    const int H   = min(gA * 128, NODES);    // 34048
    const int gB  = gbl - gA;                // 266 -> rows [H, ...)
    const int aggA = (H + 3) / 4;            // 8512 blocks (nodes [0, H))
    const int aggB = (NODES - H + 3) / 4;    // 8488 blocks (nodes [H, NODES))
    const int nbx = (NPER + 127) / 128;      // 133

    // weight swizzles
    wswz_all_kernel<<<32, 256, 0, stream>>>(W1, W2, W3, Wsw1, Wsw2, Wsw3);

    // union: partition ∪ GEMM1 (unscaled G' -> GA)
    part_gemm1_kernel<<<NBLK + gbl, 256, 0, stream>>>(
        esrc, edst, cntb, ebuf, E, NBLK, x, Wsw1, GA, NODES);

    // CSR build (inline bucket scan)
    csr_build_kernel<<<NBUK, 256, 0, stream>>>(ebuf, cntb, NBUK, offs, dinv, csr, NODES);

    // ---- layer 1 agg (SRCSCALE), split; second half unioned with GEMM2 rows [0,H) ----
    agg_kernel<true><<<aggA, 256, 0, stream>>>(GA, csr, offs, dinv, b1, A1, 0, NODES);
    agg_gemm_union_kernel<true><<<aggB + gA, 256, 0, stream>>>(
        GA, csr, offs, dinv, b1, A1, H, NODES, aggB, A1, Wsw2, GB);
    mfma_gemm_kernel<<<gB, 256, 0, stream>>>(A1, Wsw2, dinv, GB, H, NODES);

    // ---- layer 2 agg, split; second half unioned with GEMM3 rows [0,H) ----
    agg_kernel<false><<<aggA, 256, 0, stream>>>(GB, csr, offs, dinv, b2, A2, 0, NODES);
    agg_gemm_union_kernel<false><<<aggB + gA, 256, 0, stream>>>(
        GB, csr, offs, dinv, b2, A2, H, NODES, aggB, A2, Wsw3, GA);
    mfma_gemm_kernel<<<gB, 256, 0, stream>>>(A2, Wsw3, dinv, GA, H, NODES);

    // ---- layer 3 agg, split; second half unioned with pool over A1+A2 ----
    agg_kernel<false><<<aggA, 256, 0, stream>>>(GA, csr, offs, dinv, b3, A3, 0, NODES);
    agg_pool12_union_kernel<<<aggB + nbx * NB, 256, 0, stream>>>(
        GA, csr, offs, dinv, b3, A3, H, NODES, aggB, A1, A2, pmask, pooled, NPER, nbx);

    // pool A3, then MLP head
    dim3 pgrid(nbx, NB);
    pool1_kernel<<<pgrid, 64, 0, stream>>>(A3, pmask, pooled, NPER);
    mlp_kernel<<<1, 256, 0, stream>>>(pooled, lw1, lb1, lw2, lb2, lw3, lb3, lw4, lb4, out);
}

// Round 13
// 466.700 us; speedup vs baseline: 1.2229x; 1.2229x over previous
//
#include <hip/hip_runtime.h>
#include <hip/hip_bf16.h>
#include <cstdint>

#define F_IN 256
#define C 128
#define NBUK_MAX 320     // supports NODES <= 81920 (bucket = dst >> 8)
#define CHUNK 4096       // edges per partition block
#define CAP 12288        // per-bucket slab capacity (mean ~8180, max ~8500)

typedef short bf8_t __attribute__((ext_vector_type(8)));   // 8 bf16 bit-patterns (4 VGPRs)
typedef float f4_t  __attribute__((ext_vector_type(4)));

static inline size_t align256(size_t x) { return (x + 255) & ~(size_t)255; }

static __device__ inline unsigned pack_bf16(float a, float b) {
    __hip_bfloat162 h = __float22bfloat162_rn(make_float2(a, b));
    return *(unsigned*)&h;
}

static __device__ inline bf8_t pack8(float4 u0, float4 u1) {
    union { unsigned u[4]; bf8_t v; } r;
    r.u[0] = pack_bf16(u0.x, u0.y);
    r.u[1] = pack_bf16(u0.z, u0.w);
    r.u[2] = pack_bf16(u1.x, u1.y);
    r.u[3] = pack_bf16(u1.z, u1.w);
    return r.v;
}

// ---------------- union: edge partition  ∪  GEMM1 (G' = bf16(X @ W1), unscaled) -------
// R11-proven union, now 512 threads/block: partition is latency-bound (R9: 17% occ,
// ~300 GB/s effective) with fixed work per block, so 8 waves/block raises resident
// waves 50% -> ~75% at the same LDS footprint. GEMM1 path: 8 waves x one 16-row m-tile.
// dinv scaling deferred to agg1 (SRCSCALE).
__global__ __launch_bounds__(512) void part_gemm1_kernel(
        const int* __restrict__ src, const int* __restrict__ dst,
        int* __restrict__ cntb, int* __restrict__ ebuf, int E, int nblk_part,
        const float* __restrict__ X, const __hip_bfloat16* __restrict__ Wsw,
        __hip_bfloat16* __restrict__ G, int M) {
    __shared__ __align__(16) char smem[36864];
    const int tid = threadIdx.x;

    if ((int)blockIdx.x < nblk_part) {
        // ---------------- partition path (512 threads) ----------------
        int* hist = (int*)smem;                       // 320 ints
        int* base = hist + NBUK_MAX;                  // 320
        int* gbase = base + NBUK_MAX;                 // 320
        int2* stage = (int2*)(smem + 4096);           // 4096 int2 = 32 KB
        const int e0 = blockIdx.x * CHUNK;
        const int cnt = min(CHUNK, E - e0);

        for (int i = tid; i < NBUK_MAX; i += 512) hist[i] = 0;
        __syncthreads();

        int2 ev[CHUNK / 512];
        int mo[CHUNK / 512];
#pragma unroll
        for (int k = 0; k < CHUNK / 512; ++k) {
            int e = e0 + k * 512 + tid;
            if (e < E) {
                int2 v;
                v.x = src[e];
                v.y = dst[e];
                ev[k] = v;
                mo[k] = atomicAdd(&hist[v.y >> 8], 1);
            }
        }
        __syncthreads();
        // exclusive scan of hist (320 entries) by wave 0: 5 buckets/lane + shuffle scan
        if (tid < 64) {
            int acc[5];
            int s = 0;
#pragma unroll
            for (int j = 0; j < 5; ++j) {
                acc[j] = s;
                s += hist[tid * 5 + j];
            }
            int tot = s;
#pragma unroll
            for (int d = 1; d < 64; d <<= 1) {
                int o = __shfl_up(tot, d);
                if (tid >= d) tot += o;
            }
            int excl = tot - s;
#pragma unroll
            for (int j = 0; j < 5; ++j) base[tid * 5 + j] = excl + acc[j];
        }
        __syncthreads();
        for (int i = tid; i < NBUK_MAX; i += 512) {
            int h = hist[i];
            gbase[i] = h ? atomicAdd(&cntb[i], h) : 0;
        }
        __syncthreads();
#pragma unroll
        for (int k = 0; k < CHUNK / 512; ++k) {
            int e = e0 + k * 512 + tid;
            if (e < E) stage[base[ev[k].y >> 8] + mo[k]] = ev[k];
        }
        __syncthreads();
        // grouped write-out, packed 4B: (loc<<24)|src
        for (int i = tid; i < cnt; i += 512) {
            int2 e = stage[i];
            int b = e.y >> 8;
            ebuf[(size_t)b * CAP + gbase[b] + (i - base[b])] = ((e.y & 255) << 24) | e.x;
        }
    } else {
        // ------------- GEMM1 path: 8 waves x 16-row m-tile, K=256, fp32 in -------------
        char* lds = smem;   // 32 KB used
        const int gb = blockIdx.x - nblk_part;
        const int l = tid & 63;
        const int w = tid >> 6;              // 0..7
        const int lm = l & 15;
        const int lk = (l >> 4) * 8;
        const int row0 = gb * 128 + w * 16;
        const int K = F_IN;

        f4_t acc[8] = {};
        const int r = min(row0 + lm, M - 1);
        const float* xf = X + (size_t)r * K + lk;

        for (int c = 0; c < 2; ++c) {        // 2 chunks x 4 k-tiles (32 KB each)
            if (c) __syncthreads();
            const char* wsrc = (const char*)Wsw + (size_t)c * 32768;
            for (int o = tid * 16; o < 32768; o += 512 * 16)
                *(uint4*)(lds + o) = *(const uint4*)(wsrc + o);
            __syncthreads();
#pragma unroll
            for (int s2 = 0; s2 < 4; ++s2) {
                const int s = c * 4 + s2;
                float4 u0 = *(const float4*)(xf + s * 32);
                float4 u1 = *(const float4*)(xf + s * 32 + 4);
                bf8_t a = pack8(u0, u1);
                const char* bbase = lds + ((size_t)(s2 * 8) * 64 + l) * 16;
#pragma unroll
                for (int u = 0; u < 8; ++u) {
                    bf8_t b = *(const bf8_t*)(bbase + (size_t)u * 64 * 16);
                    acc[u] = __builtin_amdgcn_mfma_f32_16x16x32_bf16(a, b, acc[u], 0, 0, 0);
                }
            }
        }
        const int rbase = row0 + (l >> 4) * 4;
#pragma unroll
        for (int rr = 0; rr < 4; ++rr) {
            int row = rbase + rr;
            if (row < M) {
#pragma unroll
                for (int u = 0; u < 8; ++u)
                    G[(size_t)row * C + u * 16 + lm] = __float2bfloat16(acc[u][rr]);
            }
        }
    }
}

// ---------------- CSR build with inline bucket scan (R11-proven) ----------------
__global__ __launch_bounds__(256) void csr_build_kernel(const int* __restrict__ ebuf,
                                                        const int* __restrict__ cntb,
                                                        int nbuk,
                                                        int* __restrict__ offs,
                                                        float* __restrict__ dinv,
                                                        int* __restrict__ csr, int nodes) {
    __shared__ int hist[NBUK_MAX];
    __shared__ int basep[NBUK_MAX];
    __shared__ int deg[256];
    __shared__ int p[256];
    __shared__ int pre[257];
    __shared__ int cur[256];
    const int b = blockIdx.x;
    const int n0 = b << 8;
    const int ncnt = min(256, nodes - n0);
    const int tid = threadIdx.x;

    for (int bk = tid; bk < NBUK_MAX; bk += 256)
        hist[bk] = (bk < nbuk) ? cntb[bk] : 0;
    __syncthreads();
    if (tid < 64) {
        int acc[5];
        int s = 0;
#pragma unroll
        for (int j = 0; j < 5; ++j) {
            acc[j] = s;
            s += hist[tid * 5 + j];
        }
        int tot = s;
#pragma unroll
        for (int d = 1; d < 64; d <<= 1) {
            int o = __shfl_up(tot, d);
            if (tid >= d) tot += o;
        }
        int excl = tot - s;
#pragma unroll
        for (int j = 0; j < 5; ++j) basep[tid * 5 + j] = excl + acc[j];
    }
    __syncthreads();
    const int eb = basep[b];
    const int cntE = hist[b];
    const int* slab = ebuf + (size_t)b * CAP;

    deg[tid] = 0;
    __syncthreads();
    for (int k = tid; k < cntE; k += 256)
        atomicAdd(&deg[(unsigned)slab[k] >> 24], 1);
    __syncthreads();
    p[tid] = deg[tid];
    __syncthreads();
    for (int d = 1; d < 256; d <<= 1) {
        int v = (tid >= d) ? p[tid - d] : 0;
        __syncthreads();
        p[tid] += v;
        __syncthreads();
    }
    pre[tid + 1] = p[tid];
    if (tid == 0) pre[0] = 0;
    __syncthreads();

    for (int i = tid; i <= ncnt; i += 256)
        offs[n0 + i] = eb + pre[i] + n0 + i;
    if (tid < ncnt) {
        dinv[n0 + tid] = rsqrtf((float)(deg[tid] + 1));
        csr[eb + pre[tid] + n0 + tid] = n0 + tid;   // self-loop head
    }
    cur[tid] = 0;
    __syncthreads();
    for (int k = tid; k < cntE; k += 256) {
        int v = slab[k];
        int loc = (unsigned)v >> 24;
        int q = atomicAdd(&cur[loc], 1);
        csr[eb + pre[loc] + n0 + loc + 1 + q] = v & 0xFFFFFF;
    }
}

// ---------------- W swizzle (+ counter/pool zeroing in block 32) ----------------
static __device__ inline void swz_one(const float* __restrict__ W,
                                      __hip_bfloat16* __restrict__ Wsw, int i) {
    int l = i & 63;
    int u = (i >> 6) & 7;
    int t = i >> 9;
    int krow = t * 32 + (l >> 4) * 8;
    int col = u * 16 + (l & 15);
    unsigned packed[4];
#pragma unroll
    for (int j = 0; j < 4; ++j) {
        float a = W[(size_t)(krow + 2 * j) * C + col];
        float b = W[(size_t)(krow + 2 * j + 1) * C + col];
        packed[j] = pack_bf16(a, b);
    }
    uint4 o = make_uint4(packed[0], packed[1], packed[2], packed[3]);
    *(uint4*)(Wsw + (size_t)i * 8) = o;
}

__global__ __launch_bounds__(256) void wswz_all_kernel(const float* __restrict__ W1,
                                                       const float* __restrict__ W2,
                                                       const float* __restrict__ W3,
                                                       __hip_bfloat16* __restrict__ Wsw1,
                                                       __hip_bfloat16* __restrict__ Wsw2,
                                                       __hip_bfloat16* __restrict__ Wsw3,
                                                       int* __restrict__ cntb, int nbuk,
                                                       float* __restrict__ pooled) {
    if (blockIdx.x == 32) {   // zero pass (replaces two hipMemsetAsync dispatches)
        const int tid = threadIdx.x;
        for (int i = tid; i < nbuk; i += 256) cntb[i] = 0;
        for (int i = tid; i < 4 * C; i += 256) pooled[i] = 0.f;
        return;
    }
    int i = blockIdx.x * blockDim.x + threadIdx.x;
    if (i < 4096)      swz_one(W1, Wsw1, i);
    else if (i < 6144) swz_one(W2, Wsw2, i - 4096);
    else if (i < 8192) swz_one(W3, Wsw3, i - 6144);
}

// ---------------- MFMA GEMM (layers 2/3): G = bf16( dinv[row] * (X @ W) ), K=128 ------
__global__ __launch_bounds__(256) void mfma_gemm_kernel(const __hip_bfloat16* __restrict__ Xv,
                                                        const __hip_bfloat16* __restrict__ Wsw,
                                                        const float* __restrict__ dinv,
                                                        __hip_bfloat16* __restrict__ G,
                                                        int M) {
    __shared__ char lds[32768];
    const int tid = threadIdx.x;
    const int l = tid & 63;
    const int w = tid >> 6;
    const int lm = l & 15;
    const int lk = (l >> 4) * 8;
    const int row0 = blockIdx.x * 128 + w * 32;
    const int K = C;

    f4_t acc[2][8] = {};
    const __hip_bfloat16* xb[2];
#pragma unroll
    for (int mt = 0; mt < 2; ++mt) {
        int r = min(row0 + mt * 16 + lm, M - 1);
        xb[mt] = Xv + (size_t)r * K + lk;
    }
    bf8_t cb[2];
#pragma unroll
    for (int mt = 0; mt < 2; ++mt)
        cb[mt] = *(const bf8_t*)(xb[mt]);

    // stage full K=128 W (32 KB) once
    for (int o = tid * 16; o < 32768; o += 256 * 16)
        *(uint4*)(lds + o) = *(const uint4*)((const char*)Wsw + o);
    __syncthreads();

    for (int s = 0; s < 4; ++s) {
        bf8_t nb[2];
        if (s + 1 < 4) {
#pragma unroll
            for (int mt = 0; mt < 2; ++mt)
                nb[mt] = *(const bf8_t*)(xb[mt] + (s + 1) * 32);
        }
        const char* bbase = lds + ((size_t)(s * 8) * 64 + l) * 16;
#pragma unroll
        for (int u = 0; u < 8; ++u) {
            bf8_t b = *(const bf8_t*)(bbase + (size_t)u * 64 * 16);
#pragma unroll
            for (int mt = 0; mt < 2; ++mt)
                acc[mt][u] = __builtin_amdgcn_mfma_f32_16x16x32_bf16(cb[mt], b, acc[mt][u], 0, 0, 0);
        }
        if (s + 1 < 4) {
#pragma unroll
            for (int mt = 0; mt < 2; ++mt)
                cb[mt] = nb[mt];
        }
    }

#pragma unroll
    for (int mt = 0; mt < 2; ++mt) {
        int rbase = row0 + mt * 16 + (l >> 4) * 4;
#pragma unroll
        for (int r = 0; r < 4; ++r) {
            int row = rbase + r;
            if (row < M) {
                float dv = dinv[row];
#pragma unroll
                for (int u = 0; u < 8; ++u) {
                    float v = acc[mt][u][r] * dv;
                    G[(size_t)row * C + u * 16 + lm] = __float2bfloat16(v);
                }
            }
        }
    }
}

// ---------------- shared gather helpers (R10/R11-proven) ----------------
// Wide-gather lane layout: l = (g<<4)|q. Fabric-bound ~3.2 TB/s L2-miss leg; ONLY the
// monolithic 17000-block grid saturates it (half/coarse splits run at ~half BW —
// R4/R5/R6/R12). Atomic-fused pooling loses at >=1M atomics (R7/R8); device fences
// cost tens of us across 532 blocks (R9). Keep agg monolithic and epilogues light.
static __device__ inline void unpack_add(uint4 v, float* acc) {
    const __hip_bfloat162* hh = (const __hip_bfloat162*)&v;
#pragma unroll
    for (int t = 0; t < 4; ++t) {
        float2 f = __bfloat1622float2(hh[t]);
        acc[2 * t]     += f.x;
        acc[2 * t + 1] += f.y;
    }
}

static __device__ inline void unpack_fma(uint4 v, float dv, float* acc) {
    const __hip_bfloat162* hh = (const __hip_bfloat162*)&v;
#pragma unroll
    for (int t = 0; t < 4; ++t) {
        float2 f = __bfloat1622float2(hh[t]);
        acc[2 * t]     = fmaf(f.x, dv, acc[2 * t]);
        acc[2 * t + 1] = fmaf(f.y, dv, acc[2 * t + 1]);
    }
}

template <bool SS>
static __device__ inline void gather_rows(const char* __restrict__ Gb,
                                          const int* __restrict__ csr,
                                          const float* __restrict__ dinv,
                                          int beg, int end, int l, int g,
                                          unsigned qoff, float* acc) {
    for (int base = beg; base < end; base += 64) {
        const int cnt = min(64, end - base);
        int myidx = (l < cnt) ? csr[base + l] : 0;
        float mydv = SS ? dinv[myidx] : 1.f;
        int j = 0;
        for (; j + 16 <= cnt; j += 16) {
            int i0 = __shfl(myidx, j + g);
            int i1 = __shfl(myidx, j + 4 + g);
            int i2 = __shfl(myidx, j + 8 + g);
            int i3 = __shfl(myidx, j + 12 + g);
            uint4 v0 = *(const uint4*)(Gb + (((unsigned)i0 << 8) | qoff));
            uint4 v1 = *(const uint4*)(Gb + (((unsigned)i1 << 8) | qoff));
            uint4 v2 = *(const uint4*)(Gb + (((unsigned)i2 << 8) | qoff));
            uint4 v3 = *(const uint4*)(Gb + (((unsigned)i3 << 8) | qoff));
            if (SS) {
                float d0 = __shfl(mydv, j + g);
                float d1 = __shfl(mydv, j + 4 + g);
                float d2 = __shfl(mydv, j + 8 + g);
                float d3 = __shfl(mydv, j + 12 + g);
                unpack_fma(v0, d0, acc); unpack_fma(v1, d1, acc);
                unpack_fma(v2, d2, acc); unpack_fma(v3, d3, acc);
            } else {
                unpack_add(v0, acc); unpack_add(v1, acc);
                unpack_add(v2, acc); unpack_add(v3, acc);
            }
        }
        if (j + 8 <= cnt) {
            int i0 = __shfl(myidx, j + g);
            int i1 = __shfl(myidx, j + 4 + g);
            uint4 v0 = *(const uint4*)(Gb + (((unsigned)i0 << 8) | qoff));
            uint4 v1 = *(const uint4*)(Gb + (((unsigned)i1 << 8) | qoff));
            if (SS) {
                float d0 = __shfl(mydv, j + g);
                float d1 = __shfl(mydv, j + 4 + g);
                unpack_fma(v0, d0, acc); unpack_fma(v1, d1, acc);
            } else {
                unpack_add(v0, acc); unpack_add(v1, acc);
            }
            j += 8;
        }
        for (; j < cnt; j += 4) {
            int i0 = __shfl(myidx, j + g);
            float sc = (j + g < cnt) ? 1.f : 0.f;
            if (SS) sc *= __shfl(mydv, j + g);
            uint4 v0 = *(const uint4*)(Gb + (((unsigned)i0 << 8) | qoff));
            unpack_fma(v0, sc, acc);
        }
    }
}

// ---------------- aggregation: A[i] = relu(dinv[i]*sum_j coef_j*G[j] + bias) ----------
// 4 nodes per 256-thread block (1 wave/node). Monolithic grid — proven floor ~68-70 us.
template <bool SS>
__global__ __launch_bounds__(256) void agg_kernel(const __hip_bfloat16* __restrict__ G,
                                                  const int* __restrict__ csr,
                                                  const int* __restrict__ offs,
                                                  const float* __restrict__ dinv,
                                                  const float* __restrict__ bias,
                                                  __hip_bfloat16* __restrict__ A, int nodes) {
    const int node = blockIdx.x * 4 + (threadIdx.x >> 6);
    if (node >= nodes) return;
    const int l = threadIdx.x & 63;
    const int g = l >> 4;
    const unsigned qoff = (l & 15) * 16;
    const int beg = offs[node], end = offs[node + 1];
    float acc[8] = {};
    gather_rows<SS>((const char*)G, csr, dinv, beg, end, l, g, qoff, acc);

#pragma unroll
    for (int t = 0; t < 8; ++t) {
        acc[t] += __shfl_xor(acc[t], 16);
        acc[t] += __shfl_xor(acc[t], 32);
    }

    const float d = dinv[node];
    if (g == 0) {
        float bb[8];
        *(float4*)bb       = *(const float4*)(bias + qoff / 2);
        *(float4*)(bb + 4) = *(const float4*)(bias + qoff / 2 + 4);
        unsigned pk[4];
#pragma unroll
        for (int t = 0; t < 4; ++t) {
            float x0 = fmaxf(fmaf(acc[2 * t],     d, bb[2 * t]),     0.f);
            float x1 = fmaxf(fmaf(acc[2 * t + 1], d, bb[2 * t + 1]), 0.f);
            pk[t] = pack_bf16(x0, x1);
        }
        *(uint4*)((char*)A + (size_t)node * 256 + qoff) = make_uint4(pk[0], pk[1], pk[2], pk[3]);
    }
}

// ---------------- fused masked pool: pooled[b,c] = sum_n mask*(A1+A2+A3) ----------------
__global__ __launch_bounds__(64) void pool3_kernel(const __hip_bfloat16* __restrict__ S1,
                                                   const __hip_bfloat16* __restrict__ S2,
                                                   const __hip_bfloat16* __restrict__ S3,
                                                   const int* __restrict__ mask,
                                                   float* __restrict__ pooled, int N) {
    const int b = blockIdx.y;
    const int n0 = blockIdx.x * 128;
    const int c0 = threadIdx.x * 2;
    const int lim = min(n0 + 128, N);
    float ax = 0.f, ay = 0.f;
    for (int n = n0; n < lim; ++n) {
        if (mask[b * N + n]) {
            size_t o = ((size_t)b * N + n) * C + c0;
            float2 f1 = __bfloat1622float2(*(const __hip_bfloat162*)(S1 + o));
            float2 f2 = __bfloat1622float2(*(const __hip_bfloat162*)(S2 + o));
            float2 f3 = __bfloat1622float2(*(const __hip_bfloat162*)(S3 + o));
            ax += f1.x + f2.x + f3.x;
            ay += f1.y + f2.y + f3.y;
        }
    }
    atomicAdd(&pooled[b * C + c0], ax);
    atomicAdd(&pooled[b * C + c0 + 1], ay);
}

// ---------------- MLP head: [4,128]->256->64->16->1 ----------------
__global__ __launch_bounds__(256) void mlp_kernel(const float* __restrict__ pooled,
        const float* __restrict__ lw1, const float* __restrict__ lb1,
        const float* __restrict__ lw2, const float* __restrict__ lb2,
        const float* __restrict__ lw3, const float* __restrict__ lb3,
        const float* __restrict__ lw4, const float* __restrict__ lb4,
        float* __restrict__ out) {
    __shared__ float p[4 * 128];
    __shared__ float z1[4 * 256];
    __shared__ float z2[4 * 64];
    __shared__ float z3[4 * 16];
    const int tid = threadIdx.x;
    for (int i = tid; i < 4 * 128; i += 256) p[i] = pooled[i];
    __syncthreads();
    for (int o = tid; o < 4 * 256; o += 256) {
        int b = o >> 8, j = o & 255;
        float s = lb1[j];
        for (int k = 0; k < 128; ++k) s += p[b * 128 + k] * lw1[k * 256 + j];
        z1[o] = fmaxf(s, 0.f);
    }
    __syncthreads();
    for (int o = tid; o < 4 * 64; o += 256) {
        int b = o >> 6, j = o & 63;
        float s = lb2[j];
        for (int k = 0; k < 256; ++k) s += z1[b * 256 + k] * lw2[k * 64 + j];
        z2[o] = fmaxf(s, 0.f);
    }
    __syncthreads();
    if (tid < 64) {
        int b = tid >> 4, j = tid & 15;
        float s = lb3[j];
        for (int k = 0; k < 64; ++k) s += z2[b * 64 + k] * lw3[k * 16 + j];
        z3[tid] = fmaxf(s, 0.f);
    }
    __syncthreads();
    if (tid < 4) {
        float s = lb4[0];
        for (int k = 0; k < 16; ++k) s += z3[tid * 16 + k] * lw4[k];
        out[tid] = s;
    }
}

// ---------------- launcher ----------------

extern "C" void kernel_launch(void* const* d_in, const int* in_sizes, int n_in,
                              void* d_out, int out_size, void* d_ws, size_t ws_size,
                              hipStream_t stream) {
    const float* x    = (const float*)d_in[0];
    const int*   ei   = (const int*)d_in[1];
    const int*   pmask = (const int*)d_in[2];
    const float* W1 = (const float*)d_in[3];  const float* b1 = (const float*)d_in[4];
    const float* W2 = (const float*)d_in[5];  const float* b2 = (const float*)d_in[6];
    const float* W3 = (const float*)d_in[7];  const float* b3 = (const float*)d_in[8];
    const float* lw1 = (const float*)d_in[9];  const float* lb1 = (const float*)d_in[10];
    const float* lw2 = (const float*)d_in[11]; const float* lb2 = (const float*)d_in[12];
    const float* lw3 = (const float*)d_in[13]; const float* lb3 = (const float*)d_in[14];
    const float* lw4 = (const float*)d_in[15]; const float* lb4 = (const float*)d_in[16];
    float* out = (float*)d_out;

    const int E = in_sizes[1] / 2;
    const int NODES = in_sizes[0] / F_IN;
    const int NB = 4;
    const int NPER = NODES / NB;   // 17000
    const int NBUK = (NODES + 255) >> 8;
    const int NBLK = (E + CHUNK - 1) / CHUNK;
    const int* esrc = ei;
    const int* edst = ei + E;

    char* w = (char*)d_ws;
    size_t off = 0;
    auto alloc = [&](size_t bytes) -> void* {
        void* p = w + off;
        off = align256(off + bytes);
        return p;
    };
    float* dinv = (float*)alloc((size_t)NODES * 4);
    int*   offs = (int*)  alloc((size_t)(NODES + 1) * 4);
    int*   cntb = (int*)  alloc((size_t)NBUK * 4);
    int*   ebuf = (int*)  alloc((size_t)NBUK * CAP * 4);   // packed 4B slab entries
    int*   csr  = (int*)  alloc((size_t)(E + NODES) * 4);
    __hip_bfloat16* G   = (__hip_bfloat16*)alloc((size_t)NODES * C * 2);
    __hip_bfloat16* A1  = (__hip_bfloat16*)alloc((size_t)NODES * C * 2);
    __hip_bfloat16* A2  = (__hip_bfloat16*)alloc((size_t)NODES * C * 2);
    __hip_bfloat16* A3  = (__hip_bfloat16*)alloc((size_t)NODES * C * 2);
    __hip_bfloat16* Wsw1 = (__hip_bfloat16*)alloc((size_t)F_IN * C * 2);
    __hip_bfloat16* Wsw2 = (__hip_bfloat16*)alloc((size_t)C * C * 2);
    __hip_bfloat16* Wsw3 = (__hip_bfloat16*)alloc((size_t)C * C * 2);
    float* pooled = (float*)alloc((size_t)4 * C * 4);
    (void)ws_size; (void)n_in; (void)out_size;

    const int gblocks128 = (NODES + 127) / 128;
    const int ablocks = (NODES + 3) / 4;

    // weight swizzles + counter/pool zeroing (block 32)
    wswz_all_kernel<<<33, 256, 0, stream>>>(W1, W2, W3, Wsw1, Wsw2, Wsw3,
                                            cntb, NBUK, pooled);

    // union: partition ∪ GEMM1 (unscaled G'); gemm1 is graph-independent (512 threads)
    part_gemm1_kernel<<<NBLK + gblocks128, 512, 0, stream>>>(
        esrc, edst, cntb, ebuf, E, NBLK, x, Wsw1, G, NODES);

    // CSR build (inline bucket scan)
    csr_build_kernel<<<NBUK, 256, 0, stream>>>(ebuf, cntb, NBUK, offs, dinv, csr, NODES);

    // layer 1 aggregation: scale gathered rows by dinv[src] (G' unscaled)
    agg_kernel<true><<<ablocks, 256, 0, stream>>>(G, csr, offs, dinv, b1, A1, NODES);
    // layer 2 (K = 128)
    mfma_gemm_kernel<<<gblocks128, 256, 0, stream>>>(A1, Wsw2, dinv, G, NODES);
    agg_kernel<false><<<ablocks, 256, 0, stream>>>(G, csr, offs, dinv, b2, A2, NODES);
    // layer 3 (K = 128)
    mfma_gemm_kernel<<<gblocks128, 256, 0, stream>>>(A2, Wsw3, dinv, G, NODES);
    agg_kernel<false><<<ablocks, 256, 0, stream>>>(G, csr, offs, dinv, b3, A3, NODES);

    // fused residual pool + MLP head
    dim3 pgrid((NPER + 127) / 128, NB);
    pool3_kernel<<<pgrid, 64, 0, stream>>>(A1, A2, A3, pmask, pooled, NPER);
    mlp_kernel<<<1, 256, 0, stream>>>(pooled, lw1, lb1, lw2, lb2, lw3, lb3, lw4, lb4, out);
}